// Round 7
// baseline (2587.785 us; speedup 1.0000x reference)
//
#include <hip/hip_runtime.h>
#include <hip/hip_bf16.h>
#include <math.h>

typedef __bf16 bf16;
typedef __bf16 bf16x8 __attribute__((ext_vector_type(8)));
typedef __bf16 bf16x4 __attribute__((ext_vector_type(4)));
typedef float  f32x4 __attribute__((ext_vector_type(4)));
typedef unsigned int u32x4 __attribute__((ext_vector_type(4)));

#define NTOK 1024
#define HID  1024
#define NL   10
#define QCMAX 256

#define EPI_F32   0
#define EPI_GELU  1
#define EPI_RESID 2
#define EPI_BF16  3

// ---------------------------------------------------------------------------
// bf16 MFMA GEMM, double-buffered LDS, optional split-K, fused epilogue.
// BF32=false: B = Bt[N][K] bf16 (pre-transposed), staged linear, b128 frags.
// BF32=true : B = W[K][N] f32 (original weights!), staged as f32 [32][128]
//             rows via global_load_lds with source-side col16-XOR swizzle;
//             fragments via 8x ds_read_b32 + cvt (2-way bank alias = free).
// ---------------------------------------------------------------------------
template<int EPI, int BM, int BN, int KSPLIT, bool BF32>
__global__ __launch_bounds__(256)
void gemm_k(const bf16* __restrict__ A, int lda, long bsA,
            const void* __restrict__ Bv, int ldb, long bsB,
            void* __restrict__ Cv, int ldc, long bsC,
            const float* __restrict__ bias, int K)
{
    static_assert(!BF32 || BN == 128, "f32 B-path assumes BN=128");
    constexpr int WC  = (BM == 128) ? 2 : 4;
    constexpr int WTN = BN / WC;
    constexpr int NF  = WTN / 16;
    __shared__ bf16 Al[2][BM * 32];
    constexpr int BLBYTES = BF32 ? (2 * 32 * BN * 4) : (2 * BN * 32 * 2);
    __shared__ __align__(16) char Bl_raw[BLBYTES];

    const int t    = threadIdx.x;
    const int lane = t & 63;
    const int wv   = t >> 6;
    const int wr   = wv / WC, wc = wv % WC;
    const int lrow = lane & 15, lk = lane >> 4;
    const int n0   = blockIdx.x * BN;
    const int m0   = blockIdx.y * BM;
    const int ks   = (KSPLIT > 1) ? (blockIdx.z % KSPLIT) : 0;
    const int bz   = (KSPLIT > 1) ? (blockIdx.z / KSPLIT) : blockIdx.z;
    const int Kc   = K / KSPLIT;

    const bf16*  Ab  = A + bsA * bz + (long)ks * Kc;
    const bf16*  Bbh = BF32 ? nullptr : ((const bf16*)Bv + bsB * bz + (long)ks * Kc);
    const float* Bbf = BF32 ? ((const float*)Bv + bsB * bz + (long)ks * Kc * ldb) : nullptr;

    f32x4 acc[4][NF];
#pragma unroll
    for (int m = 0; m < 4; ++m)
#pragma unroll
        for (int n = 0; n < NF; ++n) acc[m][n] = f32x4{0.f, 0.f, 0.f, 0.f};

    const int sr = t >> 2, sc = (t & 3) * 8;

    auto stage = [&](int buf, int kk) {
#pragma unroll
        for (int i = 0; i < BM / 64; ++i)
            __builtin_amdgcn_global_load_lds(
                (const __attribute__((address_space(1))) void*)(Ab + (long)(m0 + sr + i * 64) * lda + kk + sc),
                (__attribute__((address_space(3))) void*)(&Al[buf][i * 2048 + t * 8]), 16, 0, 0);
        if (BF32) {
            float* Blf = (float*)Bl_raw + buf * (32 * BN);
            const int g = t & 31, r8 = t >> 5;
#pragma unroll
            for (int i = 0; i < 4; ++i) {
                // linear dest granule p = i*256 + t  -> row = i*8 + r8, col16 slot g>>2
                // source col16 = (g>>2) ^ (i&3)  (XOR swizzle keyed by row>>3 == i)
                const float* src = Bbf + (long)(kk + i * 8 + r8) * ldb + n0
                                 + ((((g >> 2) ^ (i & 3)) << 4) | ((g & 3) << 2));
                __builtin_amdgcn_global_load_lds(
                    (const __attribute__((address_space(1))) void*)src,
                    (__attribute__((address_space(3))) void*)(Blf + i * 1024 + t * 4), 16, 0, 0);
            }
        } else {
            bf16* Blh = (bf16*)Bl_raw + buf * (BN * 32);
#pragma unroll
            for (int i = 0; i < BN / 64; ++i)
                __builtin_amdgcn_global_load_lds(
                    (const __attribute__((address_space(1))) void*)(Bbh + (long)(n0 + sr + i * 64) * ldb + kk + sc),
                    (__attribute__((address_space(3))) void*)(Blh + i * 2048 + t * 8), 16, 0, 0);
        }
    };

    stage(0, 0);
    __syncthreads();
    int cur = 0;
    for (int k0 = 0; k0 < Kc; k0 += 32) {
        if (k0 + 32 < Kc) stage(cur ^ 1, k0 + 32);
        bf16x8 af[4], bfv[NF];
#pragma unroll
        for (int m = 0; m < 4; ++m)
            af[m] = *(const bf16x8*)&Al[cur][(wr * 64 + m * 16 + lrow) * 32 + lk * 8];
        if (BF32) {
            const float* Bf = (const float*)Bl_raw + cur * (32 * BN);
            const int cb = (wc * WTN) >> 4;
#pragma unroll
            for (int n = 0; n < NF; ++n) {
                const int c16 = (((cb + n) ^ lk) << 4) + lrow;
                bf16x8 bb;
#pragma unroll
                for (int j = 0; j < 8; ++j)
                    bb[j] = (bf16)Bf[(lk * 8 + j) * BN + c16];
                bfv[n] = bb;
            }
        } else {
            const bf16* Bh = (const bf16*)Bl_raw + cur * (BN * 32);
#pragma unroll
            for (int n = 0; n < NF; ++n)
                bfv[n] = *(const bf16x8*)&Bh[(wc * WTN + n * 16 + lrow) * 32 + lk * 8];
        }
#pragma unroll
        for (int m = 0; m < 4; ++m)
#pragma unroll
            for (int n = 0; n < NF; ++n)
                acc[m][n] = __builtin_amdgcn_mfma_f32_16x16x32_bf16(af[m], bfv[n], acc[m][n], 0, 0, 0);
        __syncthreads();
        cur ^= 1;
    }

    float* Cf = (float*)Cv + bsC * blockIdx.z;
    bf16*  Cb = (bf16*)Cv + bsC * blockIdx.z;
#pragma unroll
    for (int m = 0; m < 4; ++m)
#pragma unroll
        for (int n = 0; n < NF; ++n) {
            const int c = n0 + wc * WTN + n * 16 + lrow;
#pragma unroll
            for (int q = 0; q < 4; ++q) {
                const int r = m0 + wr * 64 + m * 16 + lk * 4 + q;
                const float v = acc[m][n][q];
                const long off = (long)r * ldc + c;
                if (EPI == EPI_F32)        Cf[off] = v;
                else if (EPI == EPI_BF16)  Cb[off] = (bf16)v;
                else if (EPI == EPI_RESID) Cf[off] += v;
                else {
                    float u = v + bias[c];
                    Cb[off] = (bf16)(0.5f * u * (1.f + erff(u * 0.70710678118654752f)));
                }
            }
        }
}

// ---------------------------------------------------------------------------
// Fused: x[row] += sum_ks parts[ks][prow] (+bias); write x; LayerNorm -> xn.
// ---------------------------------------------------------------------------
template<int NS, bool BIAS, bool SCATTER>
__global__ __launch_bounds__(256)
void ln_add_k(float* __restrict__ x, const float* __restrict__ parts, long pstride,
              const float* __restrict__ bias, const int* __restrict__ rmap,
              const float* __restrict__ w, const float* __restrict__ b,
              bf16* __restrict__ o)
{
    int row  = blockIdx.x * 4 + (threadIdx.x >> 6);
    int lane = threadIdx.x & 63;
    f32x4* xr = (f32x4*)(x + (long)row * HID) + lane * 4;
    f32x4 v[4];
#pragma unroll
    for (int i = 0; i < 4; ++i) v[i] = xr[i];

    if (NS > 0) {
        int prow = SCATTER ? rmap[row] : row;
        if (!SCATTER || prow >= 0) {
            const float* pp = parts + (long)prow * 1024 + lane * 16;
#pragma unroll
            for (int ksi = 0; ksi < NS; ++ksi) {
                const f32x4* q = (const f32x4*)(pp + (long)ksi * pstride);
#pragma unroll
                for (int i = 0; i < 4; ++i) v[i] += q[i];
            }
            if (BIAS) {
                const f32x4* bb = (const f32x4*)bias + lane * 4;
#pragma unroll
                for (int i = 0; i < 4; ++i) v[i] += bb[i];
            }
#pragma unroll
            for (int i = 0; i < 4; ++i) xr[i] = v[i];
        }
    }

    float s = 0.f;
#pragma unroll
    for (int i = 0; i < 4; ++i) s += v[i].x + v[i].y + v[i].z + v[i].w;
    for (int m = 32; m; m >>= 1) s += __shfl_xor(s, m);
    float mean = s * (1.f / 1024.f);
    f32x4 d[4];
    float ss = 0.f;
#pragma unroll
    for (int i = 0; i < 4; ++i) {
        d[i] = v[i] - mean;
        ss += d[i].x * d[i].x + d[i].y * d[i].y + d[i].z * d[i].z + d[i].w * d[i].w;
    }
    for (int m = 32; m; m >>= 1) ss += __shfl_xor(ss, m);
    float rs = rsqrtf(ss * (1.f / 1024.f) + 1e-5f);
    const f32x4* wp = (const f32x4*)w + lane * 4;
    const f32x4* bp = (const f32x4*)b + lane * 4;
    bf16x8 o0, o1;
#pragma unroll
    for (int i = 0; i < 4; ++i) {
        f32x4 wv = wp[i], bv = bp[i];
        f32x4 e;
        e.x = d[i].x * rs * wv.x + bv.x; e.y = d[i].y * rs * wv.y + bv.y;
        e.z = d[i].z * rs * wv.z + bv.z; e.w = d[i].w * rs * wv.w + bv.w;
        if (i < 2) { o0[i*4+0]=(bf16)e.x; o0[i*4+1]=(bf16)e.y; o0[i*4+2]=(bf16)e.z; o0[i*4+3]=(bf16)e.w; }
        else       { int k=(i-2)*4; o1[k+0]=(bf16)e.x; o1[k+1]=(bf16)e.y; o1[k+2]=(bf16)e.z; o1[k+3]=(bf16)e.w; }
    }
    bf16* op = o + (long)row * HID + lane * 16;
    *(bf16x8*)op = o0;
    *(bf16x8*)(op + 8) = o1;
}

// PV: Oc[r][h][d] (bf16, [256][1024]) = sum_ks pvp[(h*4+ks)][r][d]
__global__ __launch_bounds__(256)
void red4pv_k(const float* __restrict__ p, bf16* __restrict__ Oc)
{
    int i = blockIdx.x * 256 + threadIdx.x;
    int d4 = (i & 15) * 4;
    int r  = (i >> 4) & 255;
    int h  = i >> 12;
    const float* base = p + (long)(h * 4) * 16384 + r * 64 + d4;
    f32x4 s = *(const f32x4*)base;
    s += *(const f32x4*)(base + 16384);
    s += *(const f32x4*)(base + 32768);
    s += *(const f32x4*)(base + 49152);
    bf16x4 o;
    o[0] = (bf16)s.x; o[1] = (bf16)s.y; o[2] = (bf16)s.z; o[3] = (bf16)s.w;
    *(bf16x4*)(Oc + (long)r * 1024 + h * 64 + d4) = o;
}

// ---------------------------------------------------------------------------
// Local attention: one wave per (token, head). bf16 qkv input.
// ---------------------------------------------------------------------------
__global__ __launch_bounds__(256)
void lattn_k(const bf16* __restrict__ qkv, bf16* __restrict__ ao)
{
    int w    = blockIdx.x * 4 + (threadIdx.x >> 6);
    int lane = threadIdx.x & 63;
    int n = w >> 4, h = w & 15;
    int tt = n >> 8, hh = (n >> 4) & 15, ww = n & 15;

    int nj = -1;
    float dotv = 0.f;
    if (lane < 27) {
        int dt = lane / 9 - 1, dh = (lane % 9) / 3 - 1, dw = lane % 3 - 1;
        int t2 = tt + dt, h2 = hh + dh, w2 = ww + dw;
        if (t2 >= 0 && t2 < 4 && h2 >= 0 && h2 < 16 && w2 >= 0 && w2 < 16)
            nj = (t2 << 8) | (h2 << 4) | w2;
    }
    if (nj >= 0) {
        const bf16x8* qp = (const bf16x8*)(qkv + (long)n * 3072 + h * 64);
        const bf16x8* kp = (const bf16x8*)(qkv + (long)nj * 3072 + 1024 + h * 64);
#pragma unroll
        for (int i = 0; i < 8; ++i) {
            bf16x8 q8 = qp[i], k8 = kp[i];
#pragma unroll
            for (int j = 0; j < 8; ++j) dotv += (float)q8[j] * (float)k8[j];
        }
    }
    float sc = (lane < 27) ? dotv * 0.125f : -3.0e38f;
    float mx = sc;
    for (int m = 32; m; m >>= 1) mx = fmaxf(mx, __shfl_xor(mx, m));
    float e = (lane < 27) ? __expf(sc - mx) : 0.f;
    float s = e;
    for (int m = 32; m; m >>= 1) s += __shfl_xor(s, m);
    float p = e / s;

    float acc = 0.f;
    for (int j = 0; j < 27; ++j) {
        float pj = __shfl(p, j);
        int  njj = __shfl(nj, j);
        if (njj >= 0) acc += pj * (float)qkv[(long)njj * 3072 + 2048 + h * 64 + lane];
    }
    ao[(long)n * 1024 + h * 64 + lane] = (bf16)acc;
}

// ---------------------------------------------------------------------------
__global__ void compact_k(const int* __restrict__ mask, int* __restrict__ qidx,
                          int* __restrict__ rmap)
{
    int lane = threadIdx.x;
    int total = 0;
    for (int base = 0; base < 1024; base += 64) {
        int m = (mask[base + lane] != 0) ? 1 : 0;
        unsigned long long bal = __ballot(m);
        int pos = total + (int)__popcll(bal & ((1ull << lane) - 1ull));
        int ok = (m && pos < QCMAX);
        if (ok) qidx[pos] = base + lane;
        rmap[base + lane] = ok ? pos : -1;
        total += (int)__popcll(bal);
    }
    for (int i = total + lane; i < QCMAX; i += 64) qidx[i] = -1;
}

// ---------------------------------------------------------------------------
// Q/K/V head-layout build from bf16 qkv.
// ---------------------------------------------------------------------------
__global__ __launch_bounds__(256)
void qkvbuild_k(const bf16* __restrict__ qkv, const int* __restrict__ qidx,
                bf16* __restrict__ Qc, bf16* __restrict__ Kh, bf16* __restrict__ Vt)
{
    __shared__ bf16 vt[64][72];
    const int h = blockIdx.y;
    const int t = threadIdx.x;
    if (blockIdx.x < 4) {
        const int r = blockIdx.x * 64 + (t >> 2), dc = (t & 3) * 16;
        const int q = qidx[r];
        bf16x8 o0, o1;
        if (q >= 0) {
            const bf16x8* src = (const bf16x8*)(qkv + (long)q * 3072 + h * 64 + dc);
            bf16x8 a = src[0], b = src[1];
#pragma unroll
            for (int j = 0; j < 8; ++j) {
                o0[j] = (bf16)((float)a[j] * 0.125f);
                o1[j] = (bf16)((float)b[j] * 0.125f);
            }
        } else {
#pragma unroll
            for (int j = 0; j < 8; ++j) { o0[j] = (bf16)0.f; o1[j] = (bf16)0.f; }
        }
        bf16* dst = Qc + (long)h * (QCMAX * 64) + (long)r * 64 + dc;
        *(bf16x8*)dst = o0;
        *(bf16x8*)(dst + 8) = o1;
        return;
    }
    const int k0 = (blockIdx.x - 4) * 64;
    {
        const int r = t >> 2, dc = (t & 3) * 16;
        const bf16x8* kp = (const bf16x8*)(qkv + (long)(k0 + r) * 3072 + 1024 + h * 64 + dc);
        const bf16x8* vp = (const bf16x8*)(qkv + (long)(k0 + r) * 3072 + 2048 + h * 64 + dc);
        bf16x8 k0v = kp[0], k1v = kp[1];
        bf16* kd = Kh + (long)h * (NTOK * 64) + (long)(k0 + r) * 64 + dc;
        *(bf16x8*)kd = k0v;
        *(bf16x8*)(kd + 8) = k1v;
        *(bf16x8*)&vt[r][dc]     = vp[0];
        *(bf16x8*)&vt[r][dc + 8] = vp[1];
    }
    __syncthreads();
    {
        const int d = t >> 2, kc = (t & 3) * 16;
        bf16x8 o0, o1;
#pragma unroll
        for (int j = 0; j < 8; ++j) { o0[j] = vt[kc + j][d]; o1[j] = vt[kc + 8 + j][d]; }
        bf16* dst = Vt + (long)h * (64 * NTOK) + (long)d * NTOK + k0 + kc;
        *(bf16x8*)dst = o0;
        *(bf16x8*)(dst + 8) = o1;
    }
}

// ---------------------------------------------------------------------------
__global__ __launch_bounds__(256)
void softmax_k(const float* __restrict__ S, bf16* __restrict__ P)
{
    int row  = blockIdx.x * 4 + (threadIdx.x >> 6);
    int lane = threadIdx.x & 63;
    const f32x4* sp = (const f32x4*)(S + (long)row * 1024) + lane * 4;
    f32x4 v[4];
#pragma unroll
    for (int i = 0; i < 4; ++i) v[i] = sp[i];
    float mx = -3.0e38f;
#pragma unroll
    for (int i = 0; i < 4; ++i)
        mx = fmaxf(mx, fmaxf(fmaxf(v[i].x, v[i].y), fmaxf(v[i].z, v[i].w)));
    for (int m = 32; m; m >>= 1) mx = fmaxf(mx, __shfl_xor(mx, m));
    f32x4 ev[4];
    float sum = 0.f;
#pragma unroll
    for (int i = 0; i < 4; ++i) {
        ev[i].x = __expf(v[i].x - mx); ev[i].y = __expf(v[i].y - mx);
        ev[i].z = __expf(v[i].z - mx); ev[i].w = __expf(v[i].w - mx);
        sum += ev[i].x + ev[i].y + ev[i].z + ev[i].w;
    }
    for (int m = 32; m; m >>= 1) sum += __shfl_xor(sum, m);
    float inv = 1.f / sum;
    bf16x8 o0, o1;
#pragma unroll
    for (int i = 0; i < 4; ++i) {
        f32x4 e = ev[i] * inv;
        if (i < 2) { o0[i*4+0]=(bf16)e.x; o0[i*4+1]=(bf16)e.y; o0[i*4+2]=(bf16)e.z; o0[i*4+3]=(bf16)e.w; }
        else       { int k=(i-2)*4; o1[k+0]=(bf16)e.x; o1[k+1]=(bf16)e.y; o1[k+2]=(bf16)e.z; o1[k+3]=(bf16)e.w; }
    }
    bf16* op = P + (long)row * 1024 + lane * 16;
    *(bf16x8*)op = o0;
    *(bf16x8*)(op + 8) = o1;
}

// ---------------------------------------------------------------------------
__global__ __launch_bounds__(256)
void prep_k(const float* __restrict__ lat, const int* __restrict__ mask,
            const float* __restrict__ Wi, const float* __restrict__ bi,
            const float* __restrict__ et, const float* __restrict__ eh,
            const float* __restrict__ ew,
            float* __restrict__ x, float* __restrict__ tokens)
{
    __shared__ float tl[16][65];
    int t = threadIdx.x;
    int n0 = blockIdx.x * 16;
    for (int idx = t; idx < 16 * 65; idx += 256) {
        int ti = idx / 65, d = idx % 65;
        int n = n0 + ti;
        int tt = n >> 8, hh = (n >> 4) & 15, wwi = n & 15;
        float v;
        if (d < 64) {
            int c = d >> 2, ph = (d >> 1) & 1, pw = d & 1;
            v = lat[(((long)tt * 16 + c) * 32 + hh * 2 + ph) * 32 + wwi * 2 + pw];
            tokens[(long)n * 64 + d] = v;
        } else {
            v = mask[n] ? 1.f : 0.f;
        }
        tl[ti][d] = v;
    }
    __syncthreads();
    f32x4 acc[16];
#pragma unroll
    for (int i = 0; i < 16; ++i) acc[i] = f32x4{0.f, 0.f, 0.f, 0.f};
    for (int d = 0; d < 65; ++d) {
        f32x4 wv = *(const f32x4*)(Wi + (long)d * 1024 + t * 4);
#pragma unroll
        for (int ti = 0; ti < 16; ++ti) acc[ti] += tl[ti][d] * wv;
    }
    f32x4 bb = *(const f32x4*)(bi + t * 4);
    for (int ti = 0; ti < 16; ++ti) {
        int n = n0 + ti;
        int tt = n >> 8, hh = (n >> 4) & 15, wwi = n & 15;
        f32x4 pos = *(const f32x4*)(et + (long)tt * 1024 + t * 4)
                  + *(const f32x4*)(eh + (long)hh * 1024 + t * 4)
                  + *(const f32x4*)(ew + (long)wwi * 1024 + t * 4);
        *(f32x4*)(x + (long)n * 1024 + t * 4) = acc[ti] + bb + pos;
    }
}

// ---------------------------------------------------------------------------
__global__ __launch_bounds__(256)
void final_k(const bf16* __restrict__ xn, const float* __restrict__ OW,
             const float* __restrict__ ob, const float* __restrict__ tokens,
             float* __restrict__ out)
{
    __shared__ bf16 xl[8][1024];
    __shared__ float part[4][8][64];
    int t = threadIdx.x;
    int n0 = blockIdx.x * 8;
    for (int i = t; i < 1024; i += 256)
        ((u32x4*)xl)[i] = ((const u32x4*)(xn + (long)n0 * 1024))[i];
    __syncthreads();
    int j = t & 63, s = t >> 6;
    float acc[8] = {0.f, 0.f, 0.f, 0.f, 0.f, 0.f, 0.f, 0.f};
    for (int k = s * 256; k < s * 256 + 256; ++k) {
        float w = OW[(long)k * 64 + j];
#pragma unroll
        for (int ti = 0; ti < 8; ++ti) acc[ti] += (float)xl[ti][k] * w;
    }
    for (int ti = 0; ti < 8; ++ti) part[s][ti][j] = acc[ti];
    __syncthreads();
    if (s == 0) {
        for (int ti = 0; ti < 8; ++ti) {
            int n = n0 + ti;
            float v = part[0][ti][j] + part[1][ti][j] + part[2][ti][j] + part[3][ti][j]
                    + ob[j] + tokens[(long)n * 64 + j];
            int tt = n >> 8, hh = (n >> 4) & 15, wwi = n & 15;
            int c = j >> 2, ph = (j >> 1) & 1, pw = j & 1;
            out[(((long)tt * 16 + c) * 32 + hh * 2 + ph) * 32 + wwi * 2 + pw] = v;
        }
    }
}

// ---------------------------------------------------------------------------
extern "C" void kernel_launch(void* const* d_in, const int* in_sizes, int n_in,
                              void* d_out, int out_size, void* d_ws, size_t ws_size,
                              hipStream_t stream)
{
    const float* latents = (const float*)d_in[0];
    const int*   mask    = (const int*)d_in[1];
    const float* ipw  = (const float*)d_in[2];
    const float* ipb  = (const float*)d_in[3];
    const float* et   = (const float*)d_in[4];
    const float* eh   = (const float*)d_in[5];
    const float* ew   = (const float*)d_in[6];
    const float* lnlw = (const float*)d_in[7];
    const float* lnlb = (const float*)d_in[8];
    const float* lngw = (const float*)d_in[9];
    const float* lngb = (const float*)d_in[10];
    const float* lnfw = (const float*)d_in[11];
    const float* lnfb = (const float*)d_in[12];
    const float* lqkv = (const float*)d_in[13];
    const float* lout = (const float*)d_in[14];
    const float* gqkv = (const float*)d_in[15];
    const float* gout = (const float*)d_in[16];
    const float* w1   = (const float*)d_in[17];
    const float* b1   = (const float*)d_in[18];
    const float* w2   = (const float*)d_in[19];
    const float* b2   = (const float*)d_in[20];
    const float* flw  = (const float*)d_in[21];
    const float* flb  = (const float*)d_in[22];
    const float* opw  = (const float*)d_in[23];
    const float* opb  = (const float*)d_in[24];

    char* p = (char*)d_ws;
    auto alloc = [&](size_t bytes) { char* r = p; p += (bytes + 255) & ~(size_t)255; return r; };
    float* x      = (float*)alloc((size_t)4 << 20);
    bf16*  xn     = (bf16*)alloc((size_t)2 << 20);
    bf16*  qkvb   = (bf16*)alloc((size_t)6 << 20);
    bf16*  ao     = (bf16*)alloc((size_t)2 << 20);
    bf16*  hbuf   = (bf16*)alloc((size_t)8 << 20);
    float* tokens = (float*)alloc((size_t)256 << 10);
    bf16*  Qc     = (bf16*)alloc((size_t)512 << 10);
    bf16*  Kh     = (bf16*)alloc((size_t)2 << 20);
    bf16*  Vt     = (bf16*)alloc((size_t)2 << 20);
    float* S      = (float*)alloc((size_t)16 << 20);
    bf16*  P      = (bf16*)alloc((size_t)8 << 20);
    bf16*  Oc     = (bf16*)alloc((size_t)512 << 10);
    int*   qidx   = (int*)alloc(4096);
    int*   rmap   = (int*)alloc(4096);
    float* goutp  = (float*)alloc((size_t)8 * 256 * 1024 * 4);
    float* pvp    = (float*)alloc((size_t)64 * 256 * 64 * 4);
    float* f2p    = (float*)alloc((size_t)4 * 1024 * 1024 * 4);

    prep_k<<<64, 256, 0, stream>>>(latents, mask, ipw, ipb, et, eh, ew, x, tokens);
    compact_k<<<1, 64, 0, stream>>>(mask, qidx, rmap);

    for (int l = 0; l < NL; ++l) {
        const float* lqkv_l = lqkv + (long)l * 1024 * 3072;
        const float* lout_l = lout + (long)l * 1024 * 1024;
        const float* gqkv_l = gqkv + (long)l * 1024 * 3072;
        const float* gout_l = gout + (long)l * 1024 * 1024;
        const float* w1_l   = w1   + (long)l * 1024 * 4096;
        const float* w2_l   = w2   + (long)l * 4096 * 1024;

        // lnA: fold previous layer's ffn2 partials (+b2) into x, then LN
        if (l == 0)
            ln_add_k<0, false, false><<<256, 256, 0, stream>>>(
                x, nullptr, 0, nullptr, nullptr, lnlw, lnlb, xn);
        else
            ln_add_k<4, true, false><<<256, 256, 0, stream>>>(
                x, f2p, (long)1024 * 1024, b2 + (l - 1) * 1024, nullptr,
                lnlw + l * HID, lnlb + l * HID, xn);

        // local attention (weights consumed as f32 directly)
        gemm_k<EPI_BF16, 64, 128, 1, true><<<dim3(24, 16, 1), 256, 0, stream>>>(
            xn, 1024, 0, lqkv_l, 3072, 0, qkvb, 3072, 0, nullptr, 1024);
        lattn_k<<<4096, 256, 0, stream>>>(qkvb, ao);
        gemm_k<EPI_RESID, 64, 128, 1, true><<<dim3(8, 16, 1), 256, 0, stream>>>(
            ao, 1024, 0, lout_l, 1024, 0, x, 1024, 0, nullptr, 1024);

        // lnB: plain LN
        ln_add_k<0, false, false><<<256, 256, 0, stream>>>(
            x, nullptr, 0, nullptr, nullptr, lngw + l * HID, lngb + l * HID, xn);

        // global attention (masked queries)
        gemm_k<EPI_BF16, 64, 128, 1, true><<<dim3(24, 16, 1), 256, 0, stream>>>(
            xn, 1024, 0, gqkv_l, 3072, 0, qkvb, 3072, 0, nullptr, 1024);
        qkvbuild_k<<<dim3(20, 16), 256, 0, stream>>>(qkvb, qidx, Qc, Kh, Vt);
        gemm_k<EPI_F32, 64, 128, 1, false><<<dim3(8, 4, 16), 256, 0, stream>>>(
            Qc, 64, (long)256 * 64, Kh, 64, (long)1024 * 64,
            S, 1024, (long)256 * 1024, nullptr, 64);
        softmax_k<<<1024, 256, 0, stream>>>(S, P);
        gemm_k<EPI_F32, 64, 64, 4, false><<<dim3(1, 4, 64), 256, 0, stream>>>(
            P, 1024, (long)256 * 1024, Vt, 1024, (long)64 * 1024,
            pvp, 64, (long)256 * 64, nullptr, 1024);
        red4pv_k<<<256, 256, 0, stream>>>(pvp, Oc);
        gemm_k<EPI_F32, 64, 128, 8, true><<<dim3(8, 4, 8), 256, 0, stream>>>(
            Oc, 1024, 0, gout_l, 1024, 0, goutp, 1024, (long)256 * 1024, nullptr, 1024);

        // lnC: scatter-fold 8 global-out partials via rmap
        ln_add_k<8, false, true><<<256, 256, 0, stream>>>(
            x, goutp, (long)256 * 1024, nullptr, rmap,
            lnfw + l * HID, lnfb + l * HID, xn);

        // FFN
        gemm_k<EPI_GELU, 64, 128, 1, true><<<dim3(32, 16, 1), 256, 0, stream>>>(
            xn, 1024, 0, w1_l, 4096, 0, hbuf, 4096, 0, b1 + l * 4096, 1024);
        gemm_k<EPI_F32, 64, 128, 4, true><<<dim3(8, 16, 4), 256, 0, stream>>>(
            hbuf, 4096, 0, w2_l, 1024, 0, f2p, 1024, (long)1024 * 1024, nullptr, 4096);
    }

    ln_add_k<4, true, false><<<256, 256, 0, stream>>>(
        x, f2p, (long)1024 * 1024, b2 + 9 * 1024, nullptr, flw, flb, xn);
    final_k<<<128, 256, 0, stream>>>(xn, opw, opb, tokens, (float*)d_out);
}

// Round 8
// 2164.033 us; speedup vs baseline: 1.1958x; 1.1958x over previous
//
#include <hip/hip_runtime.h>
#include <hip/hip_bf16.h>
#include <math.h>

typedef __bf16 bf16;
typedef __bf16 bf16x8 __attribute__((ext_vector_type(8)));
typedef __bf16 bf16x4 __attribute__((ext_vector_type(4)));
typedef float  f32x4 __attribute__((ext_vector_type(4)));
typedef unsigned int u32x4 __attribute__((ext_vector_type(4)));

#define NTOK 1024
#define HID  1024
#define NL   10
#define QCMAX 256

#define EPI_F32   0
#define EPI_GELU  1
#define EPI_RESID 2
#define EPI_BF16  3

// ---------------------------------------------------------------------------
// All-weights convert+transpose, one launch. W[K][N] f32 -> Wt[N][K] bf16.
// (R6 version — 222 us, BW/latency bound; known good.)
// ---------------------------------------------------------------------------
__global__ __launch_bounds__(256)
void wtransall_k(const float* __restrict__ lqkv, const float* __restrict__ lout,
                 const float* __restrict__ gqkv, const float* __restrict__ gout,
                 const float* __restrict__ w1,   const float* __restrict__ w2,
                 bf16* __restrict__ lqkvT, bf16* __restrict__ loutT,
                 bf16* __restrict__ gqkvT, bf16* __restrict__ goutT,
                 bf16* __restrict__ w1T,   bf16* __restrict__ w2T)
{
    __shared__ bf16 tile[64 * 64];
    const int b = blockIdx.x;
    const float* W; bf16* O; int K, N, ti;
    if      (b < 768)  { W = lqkv; O = lqkvT; K = 1024; N = 3072; ti = b; }
    else if (b < 1024) { W = lout; O = loutT; K = 1024; N = 1024; ti = b - 768; }
    else if (b < 1792) { W = gqkv; O = gqkvT; K = 1024; N = 3072; ti = b - 1024; }
    else if (b < 2048) { W = gout; O = goutT; K = 1024; N = 1024; ti = b - 1792; }
    else if (b < 3072) { W = w1;   O = w1T;   K = 1024; N = 4096; ti = b - 2048; }
    else               { W = w2;   O = w2T;   K = 4096; N = 1024; ti = b - 3072; }
    const int ntx = N >> 6;
    const int n0 = (ti % ntx) * 64, k0 = (ti / ntx) * 64;
    const long mofs = (long)blockIdx.z * K * N;
    const float* Ws = W + mofs;
    bf16* Wo = O + mofs;
    const int t = threadIdx.x;
    {
        const int r = t >> 2, cc = (t & 3) * 16;
        const int x = (r >> 3) & 7;
        const int g0 = cc >> 3;
        const float* src = Ws + (long)(k0 + r) * N + n0 + cc;
        f32x4 a0 = *(const f32x4*)(src);
        f32x4 a1 = *(const f32x4*)(src + 4);
        f32x4 a2 = *(const f32x4*)(src + 8);
        f32x4 a3 = *(const f32x4*)(src + 12);
        bf16x8 w0, w1v;
        w0[0]=(bf16)a0.x; w0[1]=(bf16)a0.y; w0[2]=(bf16)a0.z; w0[3]=(bf16)a0.w;
        w0[4]=(bf16)a1.x; w0[5]=(bf16)a1.y; w0[6]=(bf16)a1.z; w0[7]=(bf16)a1.w;
        w1v[0]=(bf16)a2.x; w1v[1]=(bf16)a2.y; w1v[2]=(bf16)a2.z; w1v[3]=(bf16)a2.w;
        w1v[4]=(bf16)a3.x; w1v[5]=(bf16)a3.y; w1v[6]=(bf16)a3.z; w1v[7]=(bf16)a3.w;
        *(bf16x8*)&tile[r * 64 + ((g0    ) ^ x) * 8] = w0;
        *(bf16x8*)&tile[r * 64 + ((g0 | 1) ^ x) * 8] = w1v;
    }
    __syncthreads();
    {
        const int n = t >> 2, kc = (t & 3) * 16;
        const int g = n >> 3, no = n & 7;
        bf16x8 o0, o1;
#pragma unroll
        for (int j = 0; j < 8; ++j) {
            int r0 = kc + j, r1 = kc + 8 + j;
            o0[j] = tile[r0 * 64 + ((g ^ ((r0 >> 3) & 7)) * 8) + no];
            o1[j] = tile[r1 * 64 + ((g ^ ((r1 >> 3) & 7)) * 8) + no];
        }
        bf16* dst = Wo + (long)(n0 + n) * K + k0 + kc;
        *(bf16x8*)dst = o0;
        *(bf16x8*)(dst + 8) = o1;
    }
}

// ---------------------------------------------------------------------------
// bf16 MFMA GEMM with 2-deep counted-vmcnt pipeline (T4-minimal):
// loads for step i+1 stay in flight across the compute barrier of step i.
// Per-wave s_waitcnt vmcnt(NLD) + s_barrier => all waves' older stage done.
// ---------------------------------------------------------------------------
template<int EPI, int BM, int BN, int KSPLIT>
__global__ __launch_bounds__(256)
void gemm_k(const bf16* __restrict__ A, int lda, long bsA,
            const bf16* __restrict__ Bt, int ldb, long bsB,
            void* __restrict__ Cv, int ldc, long bsC,
            const float* __restrict__ bias, int K)
{
    constexpr int WC  = (BM == 128) ? 2 : 4;
    constexpr int WTN = BN / WC;
    constexpr int NF  = WTN / 16;
    constexpr int NLD = BM / 64 + BN / 64;   // global_load_lds per stage per thread
    __shared__ bf16 Al[2][BM * 32];
    __shared__ bf16 Bl[2][BN * 32];

    const int t    = threadIdx.x;
    const int lane = t & 63;
    const int wv   = t >> 6;
    const int wr   = wv / WC, wc = wv % WC;
    const int lrow = lane & 15, lk = lane >> 4;
    const int n0   = blockIdx.x * BN;
    const int m0   = blockIdx.y * BM;
    const int ks   = (KSPLIT > 1) ? (blockIdx.z % KSPLIT) : 0;
    const int bz   = (KSPLIT > 1) ? (blockIdx.z / KSPLIT) : blockIdx.z;
    const int Kc   = K / KSPLIT;

    const bf16* Ab = A  + bsA * bz + (long)ks * Kc;
    const bf16* Bb = Bt + bsB * bz + (long)ks * Kc;

    f32x4 acc[4][NF];
#pragma unroll
    for (int m = 0; m < 4; ++m)
#pragma unroll
        for (int n = 0; n < NF; ++n) acc[m][n] = f32x4{0.f, 0.f, 0.f, 0.f};

    const int sr = t >> 2, sc = (t & 3) * 8;

    auto stage = [&](int buf, int kk) {
#pragma unroll
        for (int i = 0; i < BM / 64; ++i)
            __builtin_amdgcn_global_load_lds(
                (const __attribute__((address_space(1))) void*)(Ab + (long)(m0 + sr + i * 64) * lda + kk + sc),
                (__attribute__((address_space(3))) void*)(&Al[buf][i * 2048 + t * 8]), 16, 0, 0);
#pragma unroll
        for (int i = 0; i < BN / 64; ++i)
            __builtin_amdgcn_global_load_lds(
                (const __attribute__((address_space(1))) void*)(Bb + (long)(n0 + sr + i * 64) * ldb + kk + sc),
                (__attribute__((address_space(3))) void*)(&Bl[buf][i * 2048 + t * 8]), 16, 0, 0);
    };

    const int nsteps = Kc >> 5;
    stage(0, 0);
    if (nsteps > 1) stage(1, 32);
    int cur = 0;
    for (int i = 0; i < nsteps; ++i) {
        // Wait for the OLDER stage only; the newer one (step i+1) stays in flight.
        if (i + 1 < nsteps) {
            if constexpr (NLD == 2)      asm volatile("s_waitcnt vmcnt(2)" ::: "memory");
            else if constexpr (NLD == 3) asm volatile("s_waitcnt vmcnt(3)" ::: "memory");
            else                         asm volatile("s_waitcnt vmcnt(4)" ::: "memory");
        } else {
            asm volatile("s_waitcnt vmcnt(0)" ::: "memory");
        }
        __builtin_amdgcn_s_barrier();   // all waves' stage(i) complete -> buf cur valid

        bf16x8 af[4], bfv[NF];
#pragma unroll
        for (int m = 0; m < 4; ++m)
            af[m] = *(const bf16x8*)&Al[cur][(wr * 64 + m * 16 + lrow) * 32 + lk * 8];
#pragma unroll
        for (int n = 0; n < NF; ++n)
            bfv[n] = *(const bf16x8*)&Bl[cur][(wc * WTN + n * 16 + lrow) * 32 + lk * 8];
#pragma unroll
        for (int m = 0; m < 4; ++m)
#pragma unroll
            for (int n = 0; n < NF; ++n)
                acc[m][n] = __builtin_amdgcn_mfma_f32_16x16x32_bf16(af[m], bfv[n], acc[m][n], 0, 0, 0);

        __builtin_amdgcn_s_barrier();   // all waves done reading buf cur
        if (i + 2 < nsteps) stage(cur, (i + 2) * 32);
        cur ^= 1;
    }

    float* Cf = (float*)Cv + bsC * blockIdx.z;
    bf16*  Cb = (bf16*)Cv + bsC * blockIdx.z;
#pragma unroll
    for (int m = 0; m < 4; ++m)
#pragma unroll
        for (int n = 0; n < NF; ++n) {
            const int c = n0 + wc * WTN + n * 16 + lrow;
#pragma unroll
            for (int q = 0; q < 4; ++q) {
                const int r = m0 + wr * 64 + m * 16 + lk * 4 + q;
                const float v = acc[m][n][q];
                const long off = (long)r * ldc + c;
                if (EPI == EPI_F32)        Cf[off] = v;
                else if (EPI == EPI_BF16)  Cb[off] = (bf16)v;
                else if (EPI == EPI_RESID) Cf[off] += v;
                else {
                    float u = v + bias[c];
                    Cb[off] = (bf16)(0.5f * u * (1.f + erff(u * 0.70710678118654752f)));
                }
            }
        }
}

// ---------------------------------------------------------------------------
// Fused: x[row] += sum_ks parts[ks][prow] (+bias); write x; LayerNorm -> xn.
// ---------------------------------------------------------------------------
template<int NS, bool BIAS, bool SCATTER>
__global__ __launch_bounds__(256)
void ln_add_k(float* __restrict__ x, const float* __restrict__ parts, long pstride,
              const float* __restrict__ bias, const int* __restrict__ rmap,
              const float* __restrict__ w, const float* __restrict__ b,
              bf16* __restrict__ o)
{
    int row  = blockIdx.x * 4 + (threadIdx.x >> 6);
    int lane = threadIdx.x & 63;
    f32x4* xr = (f32x4*)(x + (long)row * HID) + lane * 4;
    f32x4 v[4];
#pragma unroll
    for (int i = 0; i < 4; ++i) v[i] = xr[i];

    if (NS > 0) {
        int prow = SCATTER ? rmap[row] : row;
        if (!SCATTER || prow >= 0) {
            const float* pp = parts + (long)prow * 1024 + lane * 16;
#pragma unroll
            for (int ksi = 0; ksi < NS; ++ksi) {
                const f32x4* q = (const f32x4*)(pp + (long)ksi * pstride);
#pragma unroll
                for (int i = 0; i < 4; ++i) v[i] += q[i];
            }
            if (BIAS) {
                const f32x4* bb = (const f32x4*)bias + lane * 4;
#pragma unroll
                for (int i = 0; i < 4; ++i) v[i] += bb[i];
            }
#pragma unroll
            for (int i = 0; i < 4; ++i) xr[i] = v[i];
        }
    }

    float s = 0.f;
#pragma unroll
    for (int i = 0; i < 4; ++i) s += v[i].x + v[i].y + v[i].z + v[i].w;
    for (int m = 32; m; m >>= 1) s += __shfl_xor(s, m);
    float mean = s * (1.f / 1024.f);
    f32x4 d[4];
    float ss = 0.f;
#pragma unroll
    for (int i = 0; i < 4; ++i) {
        d[i] = v[i] - mean;
        ss += d[i].x * d[i].x + d[i].y * d[i].y + d[i].z * d[i].z + d[i].w * d[i].w;
    }
    for (int m = 32; m; m >>= 1) ss += __shfl_xor(ss, m);
    float rs = rsqrtf(ss * (1.f / 1024.f) + 1e-5f);
    const f32x4* wp = (const f32x4*)w + lane * 4;
    const f32x4* bp = (const f32x4*)b + lane * 4;
    bf16x8 o0, o1;
#pragma unroll
    for (int i = 0; i < 4; ++i) {
        f32x4 wv = wp[i], bv = bp[i];
        f32x4 e;
        e.x = d[i].x * rs * wv.x + bv.x; e.y = d[i].y * rs * wv.y + bv.y;
        e.z = d[i].z * rs * wv.z + bv.z; e.w = d[i].w * rs * wv.w + bv.w;
        if (i < 2) { o0[i*4+0]=(bf16)e.x; o0[i*4+1]=(bf16)e.y; o0[i*4+2]=(bf16)e.z; o0[i*4+3]=(bf16)e.w; }
        else       { int k=(i-2)*4; o1[k+0]=(bf16)e.x; o1[k+1]=(bf16)e.y; o1[k+2]=(bf16)e.z; o1[k+3]=(bf16)e.w; }
    }
    bf16* op = o + (long)row * HID + lane * 16;
    *(bf16x8*)op = o0;
    *(bf16x8*)(op + 8) = o1;
}

// ---------------------------------------------------------------------------
// Local attention: one wave per (token, head). bf16 qkv input.
// ---------------------------------------------------------------------------
__global__ __launch_bounds__(256)
void lattn_k(const bf16* __restrict__ qkv, bf16* __restrict__ ao)
{
    int w    = blockIdx.x * 4 + (threadIdx.x >> 6);
    int lane = threadIdx.x & 63;
    int n = w >> 4, h = w & 15;
    int tt = n >> 8, hh = (n >> 4) & 15, ww = n & 15;

    int nj = -1;
    float dotv = 0.f;
    if (lane < 27) {
        int dt = lane / 9 - 1, dh = (lane % 9) / 3 - 1, dw = lane % 3 - 1;
        int t2 = tt + dt, h2 = hh + dh, w2 = ww + dw;
        if (t2 >= 0 && t2 < 4 && h2 >= 0 && h2 < 16 && w2 >= 0 && w2 < 16)
            nj = (t2 << 8) | (h2 << 4) | w2;
    }
    if (nj >= 0) {
        const bf16x8* qp = (const bf16x8*)(qkv + (long)n * 3072 + h * 64);
        const bf16x8* kp = (const bf16x8*)(qkv + (long)nj * 3072 + 1024 + h * 64);
#pragma unroll
        for (int i = 0; i < 8; ++i) {
            bf16x8 q8 = qp[i], k8 = kp[i];
#pragma unroll
            for (int j = 0; j < 8; ++j) dotv += (float)q8[j] * (float)k8[j];
        }
    }
    float sc = (lane < 27) ? dotv * 0.125f : -3.0e38f;
    float mx = sc;
    for (int m = 32; m; m >>= 1) mx = fmaxf(mx, __shfl_xor(mx, m));
    float e = (lane < 27) ? __expf(sc - mx) : 0.f;
    float s = e;
    for (int m = 32; m; m >>= 1) s += __shfl_xor(s, m);
    float p = e / s;

    float acc = 0.f;
    for (int j = 0; j < 27; ++j) {
        float pj = __shfl(p, j);
        int  njj = __shfl(nj, j);
        if (njj >= 0) acc += pj * (float)qkv[(long)njj * 3072 + 2048 + h * 64 + lane];
    }
    ao[(long)n * 1024 + h * 64 + lane] = (bf16)acc;
}

// ---------------------------------------------------------------------------
__global__ void compact_k(const int* __restrict__ mask, int* __restrict__ qidx,
                          int* __restrict__ rmap)
{
    int lane = threadIdx.x;
    int total = 0;
    for (int base = 0; base < 1024; base += 64) {
        int m = (mask[base + lane] != 0) ? 1 : 0;
        unsigned long long bal = __ballot(m);
        int pos = total + (int)__popcll(bal & ((1ull << lane) - 1ull));
        int ok = (m && pos < QCMAX);
        if (ok) qidx[pos] = base + lane;
        rmap[base + lane] = ok ? pos : -1;
        total += (int)__popcll(bal);
    }
    for (int i = total + lane; i < QCMAX; i += 64) qidx[i] = -1;
}

// ---------------------------------------------------------------------------
// Q/K/V head-layout build from bf16 qkv.
// ---------------------------------------------------------------------------
__global__ __launch_bounds__(256)
void qkvbuild_k(const bf16* __restrict__ qkv, const int* __restrict__ qidx,
                bf16* __restrict__ Qc, bf16* __restrict__ Kh, bf16* __restrict__ Vt)
{
    __shared__ bf16 vt[64][72];
    const int h = blockIdx.y;
    const int t = threadIdx.x;
    if (blockIdx.x < 4) {
        const int r = blockIdx.x * 64 + (t >> 2), dc = (t & 3) * 16;
        const int q = qidx[r];
        bf16x8 o0, o1;
        if (q >= 0) {
            const bf16x8* src = (const bf16x8*)(qkv + (long)q * 3072 + h * 64 + dc);
            bf16x8 a = src[0], b = src[1];
#pragma unroll
            for (int j = 0; j < 8; ++j) {
                o0[j] = (bf16)((float)a[j] * 0.125f);
                o1[j] = (bf16)((float)b[j] * 0.125f);
            }
        } else {
#pragma unroll
            for (int j = 0; j < 8; ++j) { o0[j] = (bf16)0.f; o1[j] = (bf16)0.f; }
        }
        bf16* dst = Qc + (long)h * (QCMAX * 64) + (long)r * 64 + dc;
        *(bf16x8*)dst = o0;
        *(bf16x8*)(dst + 8) = o1;
        return;
    }
    const int k0 = (blockIdx.x - 4) * 64;
    {
        const int r = t >> 2, dc = (t & 3) * 16;
        const bf16x8* kp = (const bf16x8*)(qkv + (long)(k0 + r) * 3072 + 1024 + h * 64 + dc);
        const bf16x8* vp = (const bf16x8*)(qkv + (long)(k0 + r) * 3072 + 2048 + h * 64 + dc);
        bf16x8 k0v = kp[0], k1v = kp[1];
        bf16* kd = Kh + (long)h * (NTOK * 64) + (long)(k0 + r) * 64 + dc;
        *(bf16x8*)kd = k0v;
        *(bf16x8*)(kd + 8) = k1v;
        *(bf16x8*)&vt[r][dc]     = vp[0];
        *(bf16x8*)&vt[r][dc + 8] = vp[1];
    }
    __syncthreads();
    {
        const int d = t >> 2, kc = (t & 3) * 16;
        bf16x8 o0, o1;
#pragma unroll
        for (int j = 0; j < 8; ++j) { o0[j] = vt[kc + j][d]; o1[j] = vt[kc + 8 + j][d]; }
        bf16* dst = Vt + (long)h * (64 * NTOK) + (long)d * NTOK + k0 + kc;
        *(bf16x8*)dst = o0;
        *(bf16x8*)(dst + 8) = o1;
    }
}

// ---------------------------------------------------------------------------
__global__ __launch_bounds__(256)
void softmax_k(const float* __restrict__ S, bf16* __restrict__ P)
{
    int row  = blockIdx.x * 4 + (threadIdx.x >> 6);
    int lane = threadIdx.x & 63;
    const f32x4* sp = (const f32x4*)(S + (long)row * 1024) + lane * 4;
    f32x4 v[4];
#pragma unroll
    for (int i = 0; i < 4; ++i) v[i] = sp[i];
    float mx = -3.0e38f;
#pragma unroll
    for (int i = 0; i < 4; ++i)
        mx = fmaxf(mx, fmaxf(fmaxf(v[i].x, v[i].y), fmaxf(v[i].z, v[i].w)));
    for (int m = 32; m; m >>= 1) mx = fmaxf(mx, __shfl_xor(mx, m));
    f32x4 ev[4];
    float sum = 0.f;
#pragma unroll
    for (int i = 0; i < 4; ++i) {
        ev[i].x = __expf(v[i].x - mx); ev[i].y = __expf(v[i].y - mx);
        ev[i].z = __expf(v[i].z - mx); ev[i].w = __expf(v[i].w - mx);
        sum += ev[i].x + ev[i].y + ev[i].z + ev[i].w;
    }
    for (int m = 32; m; m >>= 1) sum += __shfl_xor(sum, m);
    float inv = 1.f / sum;
    bf16x8 o0, o1;
#pragma unroll
    for (int i = 0; i < 4; ++i) {
        f32x4 e = ev[i] * inv;
        if (i < 2) { o0[i*4+0]=(bf16)e.x; o0[i*4+1]=(bf16)e.y; o0[i*4+2]=(bf16)e.z; o0[i*4+3]=(bf16)e.w; }
        else       { int k=(i-2)*4; o1[k+0]=(bf16)e.x; o1[k+1]=(bf16)e.y; o1[k+2]=(bf16)e.z; o1[k+3]=(bf16)e.w; }
    }
    bf16* op = P + (long)row * 1024 + lane * 16;
    *(bf16x8*)op = o0;
    *(bf16x8*)(op + 8) = o1;
}

// ---------------------------------------------------------------------------
__global__ __launch_bounds__(256)
void prep_k(const float* __restrict__ lat, const int* __restrict__ mask,
            const float* __restrict__ Wi, const float* __restrict__ bi,
            const float* __restrict__ et, const float* __restrict__ eh,
            const float* __restrict__ ew,
            float* __restrict__ x, float* __restrict__ tokens)
{
    __shared__ float tl[16][65];
    int t = threadIdx.x;
    int n0 = blockIdx.x * 16;
    for (int idx = t; idx < 16 * 65; idx += 256) {
        int ti = idx / 65, d = idx % 65;
        int n = n0 + ti;
        int tt = n >> 8, hh = (n >> 4) & 15, wwi = n & 15;
        float v;
        if (d < 64) {
            int c = d >> 2, ph = (d >> 1) & 1, pw = d & 1;
            v = lat[(((long)tt * 16 + c) * 32 + hh * 2 + ph) * 32 + wwi * 2 + pw];
            tokens[(long)n * 64 + d] = v;
        } else {
            v = mask[n] ? 1.f : 0.f;
        }
        tl[ti][d] = v;
    }
    __syncthreads();
    f32x4 acc[16];
#pragma unroll
    for (int i = 0; i < 16; ++i) acc[i] = f32x4{0.f, 0.f, 0.f, 0.f};
    for (int d = 0; d < 65; ++d) {
        f32x4 wv = *(const f32x4*)(Wi + (long)d * 1024 + t * 4);
#pragma unroll
        for (int ti = 0; ti < 16; ++ti) acc[ti] += tl[ti][d] * wv;
    }
    f32x4 bb = *(const f32x4*)(bi + t * 4);
    for (int ti = 0; ti < 16; ++ti) {
        int n = n0 + ti;
        int tt = n >> 8, hh = (n >> 4) & 15, wwi = n & 15;
        f32x4 pos = *(const f32x4*)(et + (long)tt * 1024 + t * 4)
                  + *(const f32x4*)(eh + (long)hh * 1024 + t * 4)
                  + *(const f32x4*)(ew + (long)wwi * 1024 + t * 4);
        *(f32x4*)(x + (long)n * 1024 + t * 4) = acc[ti] + bb + pos;
    }
}

// ---------------------------------------------------------------------------
__global__ __launch_bounds__(256)
void final_k(const bf16* __restrict__ xn, const float* __restrict__ OW,
             const float* __restrict__ ob, const float* __restrict__ tokens,
             float* __restrict__ out)
{
    __shared__ bf16 xl[8][1024];
    __shared__ float part[4][8][64];
    int t = threadIdx.x;
    int n0 = blockIdx.x * 8;
    for (int i = t; i < 1024; i += 256)
        ((u32x4*)xl)[i] = ((const u32x4*)(xn + (long)n0 * 1024))[i];
    __syncthreads();
    int j = t & 63, s = t >> 6;
    float acc[8] = {0.f, 0.f, 0.f, 0.f, 0.f, 0.f, 0.f, 0.f};
    for (int k = s * 256; k < s * 256 + 256; ++k) {
        float w = OW[(long)k * 64 + j];
#pragma unroll
        for (int ti = 0; ti < 8; ++ti) acc[ti] += (float)xl[ti][k] * w;
    }
    for (int ti = 0; ti < 8; ++ti) part[s][ti][j] = acc[ti];
    __syncthreads();
    if (s == 0) {
        for (int ti = 0; ti < 8; ++ti) {
            int n = n0 + ti;
            float v = part[0][ti][j] + part[1][ti][j] + part[2][ti][j] + part[3][ti][j]
                    + ob[j] + tokens[(long)n * 64 + j];
            int tt = n >> 8, hh = (n >> 4) & 15, wwi = n & 15;
            int c = j >> 2, ph = (j >> 1) & 1, pw = j & 1;
            out[(((long)tt * 16 + c) * 32 + hh * 2 + ph) * 32 + wwi * 2 + pw] = v;
        }
    }
}

// ---------------------------------------------------------------------------
extern "C" void kernel_launch(void* const* d_in, const int* in_sizes, int n_in,
                              void* d_out, int out_size, void* d_ws, size_t ws_size,
                              hipStream_t stream)
{
    const float* latents = (const float*)d_in[0];
    const int*   mask    = (const int*)d_in[1];
    const float* ipw  = (const float*)d_in[2];
    const float* ipb  = (const float*)d_in[3];
    const float* et   = (const float*)d_in[4];
    const float* eh   = (const float*)d_in[5];
    const float* ew   = (const float*)d_in[6];
    const float* lnlw = (const float*)d_in[7];
    const float* lnlb = (const float*)d_in[8];
    const float* lngw = (const float*)d_in[9];
    const float* lngb = (const float*)d_in[10];
    const float* lnfw = (const float*)d_in[11];
    const float* lnfb = (const float*)d_in[12];
    const float* lqkv = (const float*)d_in[13];
    const float* lout = (const float*)d_in[14];
    const float* gqkv = (const float*)d_in[15];
    const float* gout = (const float*)d_in[16];
    const float* w1   = (const float*)d_in[17];
    const float* b1   = (const float*)d_in[18];
    const float* w2   = (const float*)d_in[19];
    const float* b2   = (const float*)d_in[20];
    const float* flw  = (const float*)d_in[21];
    const float* flb  = (const float*)d_in[22];
    const float* opw  = (const float*)d_in[23];
    const float* opb  = (const float*)d_in[24];

    char* p = (char*)d_ws;
    auto alloc = [&](size_t bytes) { char* r = p; p += (bytes + 255) & ~(size_t)255; return r; };
    float* x      = (float*)alloc((size_t)4 << 20);
    bf16*  xn     = (bf16*)alloc((size_t)2 << 20);
    bf16*  qkvb   = (bf16*)alloc((size_t)6 << 20);
    bf16*  ao     = (bf16*)alloc((size_t)2 << 20);
    bf16*  hbuf   = (bf16*)alloc((size_t)8 << 20);
    float* tokens = (float*)alloc((size_t)256 << 10);
    bf16*  Qc     = (bf16*)alloc((size_t)512 << 10);
    bf16*  Kh     = (bf16*)alloc((size_t)2 << 20);
    bf16*  Vt     = (bf16*)alloc((size_t)2 << 20);
    float* S      = (float*)alloc((size_t)16 << 20);
    bf16*  P      = (bf16*)alloc((size_t)8 << 20);
    bf16*  Oc     = (bf16*)alloc((size_t)512 << 10);
    int*   qidx   = (int*)alloc(4096);
    int*   rmap   = (int*)alloc(4096);
    float* goutp  = (float*)alloc((size_t)8 * 256 * 1024 * 4);
    float* f2p    = (float*)alloc((size_t)4 * 1024 * 1024 * 4);
    bf16* lqkvT = (bf16*)alloc((size_t)10 * 3072 * 1024 * 2);
    bf16* loutT = (bf16*)alloc((size_t)10 * 1024 * 1024 * 2);
    bf16* gqkvT = (bf16*)alloc((size_t)10 * 3072 * 1024 * 2);
    bf16* goutT = (bf16*)alloc((size_t)10 * 1024 * 1024 * 2);
    bf16* w1T   = (bf16*)alloc((size_t)10 * 4096 * 1024 * 2);
    bf16* w2T   = (bf16*)alloc((size_t)10 * 1024 * 4096 * 2);

    wtransall_k<<<dim3(4096, 1, NL), 256, 0, stream>>>(
        lqkv, lout, gqkv, gout, w1, w2, lqkvT, loutT, gqkvT, goutT, w1T, w2T);

    prep_k<<<64, 256, 0, stream>>>(latents, mask, ipw, ipb, et, eh, ew, x, tokens);
    compact_k<<<1, 64, 0, stream>>>(mask, qidx, rmap);

    for (int l = 0; l < NL; ++l) {
        const long wq  = (long)l * 3072 * 1024;
        const long wo  = (long)l * 1024 * 1024;
        const long wf1 = (long)l * 4096 * 1024;

        // lnA: fold previous layer's ffn2 partials (+b2) into x, then LN
        if (l == 0)
            ln_add_k<0, false, false><<<256, 256, 0, stream>>>(
                x, nullptr, 0, nullptr, nullptr, lnlw, lnlb, xn);
        else
            ln_add_k<4, true, false><<<256, 256, 0, stream>>>(
                x, f2p, (long)1024 * 1024, b2 + (l - 1) * 1024, nullptr,
                lnlw + l * HID, lnlb + l * HID, xn);

        // local attention (qkv in bf16)
        gemm_k<EPI_BF16, 64, 128, 1><<<dim3(24, 16, 1), 256, 0, stream>>>(
            xn, 1024, 0, lqkvT + wq, 1024, 0, qkvb, 3072, 0, nullptr, 1024);
        lattn_k<<<4096, 256, 0, stream>>>(qkvb, ao);
        gemm_k<EPI_RESID, 64, 128, 1><<<dim3(8, 16, 1), 256, 0, stream>>>(
            ao, 1024, 0, loutT + wo, 1024, 0, x, 1024, 0, nullptr, 1024);

        // lnB: plain LN
        ln_add_k<0, false, false><<<256, 256, 0, stream>>>(
            x, nullptr, 0, nullptr, nullptr, lngw + l * HID, lngb + l * HID, xn);

        // global attention (masked queries), wide pipeline
        gemm_k<EPI_BF16, 64, 128, 1><<<dim3(24, 16, 1), 256, 0, stream>>>(
            xn, 1024, 0, gqkvT + wq, 1024, 0, qkvb, 3072, 0, nullptr, 1024);
        qkvbuild_k<<<dim3(20, 16), 256, 0, stream>>>(qkvb, qidx, Qc, Kh, Vt);
        gemm_k<EPI_F32, 64, 128, 1><<<dim3(8, 4, 16), 256, 0, stream>>>(
            Qc, 64, (long)256 * 64, Kh, 64, (long)1024 * 64,
            S, 1024, (long)256 * 1024, nullptr, 64);
        softmax_k<<<1024, 256, 0, stream>>>(S, P);
        gemm_k<EPI_BF16, 64, 64, 1><<<dim3(1, 4, 16), 256, 0, stream>>>(
            P, 1024, (long)256 * 1024, Vt, 1024, (long)64 * 1024,
            Oc, 1024, 64, nullptr, 1024);
        gemm_k<EPI_F32, 64, 128, 8><<<dim3(8, 4, 8), 256, 0, stream>>>(
            Oc, 1024, 0, goutT + wo, 1024, 0, goutp, 1024, (long)256 * 1024, nullptr, 1024);

        // lnC: scatter-fold 8 global-out partials via rmap
        ln_add_k<8, false, true><<<256, 256, 0, stream>>>(
            x, goutp, (long)256 * 1024, nullptr, rmap,
            lnfw + l * HID, lnfb + l * HID, xn);

        // FFN
        gemm_k<EPI_GELU, 64, 128, 1><<<dim3(32, 16, 1), 256, 0, stream>>>(
            xn, 1024, 0, w1T + wf1, 1024, 0, hbuf, 4096, 0, b1 + l * 4096, 1024);
        gemm_k<EPI_F32, 64, 128, 4><<<dim3(8, 16, 4), 256, 0, stream>>>(
            hbuf, 4096, 0, w2T + wf1, 4096, 0, f2p, 1024, (long)1024 * 1024, nullptr, 4096);
    }

    ln_add_k<4, true, false><<<256, 256, 0, stream>>>(
        x, f2p, (long)1024 * 1024, b2 + 9 * 1024, nullptr, flw, flb, xn);
    final_k<<<128, 256, 0, stream>>>(xn, opw, opb, tokens, (float*)d_out);
}